// Round 11
// baseline (135.731 us; speedup 1.0000x reference)
//
#include <hip/hip_runtime.h>
#include <stdint.h>

#define B_ROWS 4096
#define OUTF   1024
#define INF    1024
#define KTOT   3072          // 3 * 1024
#define KHALF  1536
#define BN_EPS 1e-5f
#define BM 128
#define BN 128
#define BK 32
#define NSTEP (KHALF / BK)   // 48

typedef short  short8  __attribute__((ext_vector_type(8)));
typedef float  floatx4 __attribute__((ext_vector_type(4)));

struct alignas(8) s4 { short x, y, z, w; };

// s_waitcnt SIMM16 (gfx9/gfx950): vmcnt[3:0]=imm[3:0], expcnt=imm[6:4],
// lgkmcnt=imm[11:8], vmcnt[5:4]=imm[15:14].
#define WAIT_VM4 0x0F74
#define WAIT_VM2 0x0F72
#define WAIT_VM0 0x0F70

__device__ __forceinline__ short f2bf(float f) {
  union { float f; uint32_t u; } cv; cv.f = f;
  uint32_t u = cv.u;
  uint32_t r = (u + 0x7fffu + ((u >> 16) & 1u)) >> 16;  // RNE
  return (short)r;
}

__device__ __forceinline__ void load_lds16(const void* g, void* l) {
  __builtin_amdgcn_global_load_lds(
      (const __attribute__((address_space(1))) uint32_t*)(uintptr_t)g,
      (__attribute__((address_space(3))) uint32_t*)(uint32_t)(uintptr_t)l,
      16, 0, 0);
}

// ---- 1. prep: x -> bf16 {x,x^2,x^3} (Xb), c1|c2|c3 -> bf16 Wb --------------
// bias skipped: a per-column constant shifts the batch mean and is cancelled
// exactly by BatchNorm (variance unaffected). [verified R6..R10]
__global__ void prep_all(const float4* __restrict__ x4,
                         const float4* __restrict__ c1, const float4* __restrict__ c2,
                         const float4* __restrict__ c3,
                         short* __restrict__ Xb, short* __restrict__ Wb) {
  int b = blockIdx.x;
  if (b < 4096) {
    int idx = b * 256 + threadIdx.x;           // 1,048,576 float4 of x
    float4 v = x4[idx];
    int row = idx >> 8;
    int c   = (idx & 255) << 2;
    size_t base = (size_t)row * KTOT + c;
    s4 p1 = { f2bf(v.x), f2bf(v.y), f2bf(v.z), f2bf(v.w) };
    float ax = v.x * v.x, ay = v.y * v.y, az = v.z * v.z, aw = v.w * v.w;
    s4 p2 = { f2bf(ax), f2bf(ay), f2bf(az), f2bf(aw) };
    s4 p3 = { f2bf(ax * v.x), f2bf(ay * v.y), f2bf(az * v.z), f2bf(aw * v.w) };
    *(s4*)&Xb[base]        = p1;
    *(s4*)&Xb[base + 1024] = p2;
    *(s4*)&Xb[base + 2048] = p3;
  } else {
    int idx = (b - 4096) * 256 + threadIdx.x;  // 262,144 float4 per weight
    int row = idx >> 8;
    int c   = (idx & 255) << 2;
    size_t base = (size_t)row * KTOT + c;
    float4 a = c1[idx], bb = c2[idx], d = c3[idx];
    s4 p1 = { f2bf(a.x),  f2bf(a.y),  f2bf(a.z),  f2bf(a.w)  };
    s4 p2 = { f2bf(bb.x), f2bf(bb.y), f2bf(bb.z), f2bf(bb.w) };
    s4 p3 = { f2bf(d.x),  f2bf(d.y),  f2bf(d.z),  f2bf(d.w)  };
    *(s4*)&Wb[base]        = p1;
    *(s4*)&Wb[base + 1024] = p2;
    *(s4*)&Wb[base + 2048] = p3;
  }
}

// ---- 2. GEMM split-K=2: 512 blocks of 128x128x1536, 2 blocks/CU ------------
// Evidence R2/m97: staging rate tracks INDEPENDENT blocks per CU (17.6-20
// B/cyc at 2-3 blk/CU vs 13 at 1). BK=32, 4 LDS buffers = 64 KB/block so 2
// blocks co-reside; 3-deep prefetch, wait vmcnt(4) per step (own tile's 2
// loads done, 2 tiles in flight). Super-row swizzle: 2 rows = 128 B = 8
// 16B-slots; physical slot q of super-row R holds logical slot q ^ (R & 7)
// -> exact 2-way bank aliasing (free, m136). Writes fp32 partials P[kp].
__global__ __launch_bounds__(512, 4) void gemm_poly(
    const short* __restrict__ Xb, const short* __restrict__ Wb,
    float* __restrict__ P0, float* __restrict__ P1) {
  __shared__ __align__(16) short As[4][BM * BK];   // 4 x 8 KB
  __shared__ __align__(16) short Bs[4][BN * BK];   // 4 x 8 KB   (64 KB total)
  const int tid  = threadIdx.x;
  const int lane = tid & 63;
  const int wave = tid >> 6;
  const int wr = wave >> 2;            // 0..1 : 64-row half
  const int wc = wave & 3;             // 0..3 : 32-col quarter
  const int lb   = blockIdx.x;
  const int xcd  = lb & 7;
  const int rest = lb >> 3;            // 0..63
  const int kp   = rest & 1;
  const int sl   = rest >> 1;          // 0..31
  const int bx   = sl & 7;
  const int by   = xcd * 4 + (sl >> 3);
  const int row0 = by * BM;
  const int col0 = bx * BN;
  const short* Ag = Xb + (size_t)row0 * KTOT + kp * KHALF;
  const short* Bg = Wb + (size_t)col0 * KTOT + kp * KHALF;
  const int frag_m = lane & 15;
  const int sel = lane >> 4;           // k-quarter (16B slot) of the K=32 step
  floatx4 acc[4][2] = {};

  // staging: thread tid owns physical chunk tid (LDS addr tid*16B) of both
  // tiles. Super-row R = tid>>3, slot q = tid&7, logical ls = q ^ (R&7),
  // source row = R*2 + (ls>>2), k-offset = (ls&3)*8.
  const int Rr = tid >> 3, qq = tid & 7;
  const int ls = qq ^ (Rr & 7);
  const int soff = (Rr * 2 + (ls >> 2)) * KTOT + (ls & 3) * 8;
  const int ldst = tid * 8;

  // prologue: stage tiles 0,1,2 (2 loads per thread per tile, in order)
  #pragma unroll
  for (int t = 0; t < 3; ++t) {
    load_lds16(Ag + soff + t * BK, &As[t][ldst]);
    load_lds16(Bg + soff + t * BK, &Bs[t][ldst]);
  }

#define GSTEP(CUR, PRE, KT_PRE, DO_PRE, WAITIMM)                              \
  {                                                                           \
    __builtin_amdgcn_s_waitcnt(WAITIMM);                                      \
    __builtin_amdgcn_s_barrier();                                             \
    if (DO_PRE) {                                                             \
      load_lds16(Ag + soff + (KT_PRE), &As[PRE][ldst]);                       \
      load_lds16(Bg + soff + (KT_PRE), &Bs[PRE][ldst]);                       \
    }                                                                         \
    short8 af[4], bfr[2];                                                     \
    _Pragma("unroll")                                                         \
    for (int i = 0; i < 4; ++i) {                                             \
      int r = wr * 64 + i * 16 + frag_m;                                      \
      int q = (((r & 1) << 2) | sel) ^ ((r >> 1) & 7);                        \
      af[i] = *(const short8*)&As[CUR][(r >> 1) * 64 + q * 8];                \
    }                                                                         \
    _Pragma("unroll")                                                         \
    for (int j = 0; j < 2; ++j) {                                             \
      int r = wc * 32 + j * 16 + frag_m;                                      \
      int q = (((r & 1) << 2) | sel) ^ ((r >> 1) & 7);                        \
      bfr[j] = *(const short8*)&Bs[CUR][(r >> 1) * 64 + q * 8];               \
    }                                                                         \
    _Pragma("unroll")                                                         \
    for (int i = 0; i < 4; ++i)                                               \
      _Pragma("unroll")                                                       \
      for (int j = 0; j < 2; ++j)                                             \
        acc[i][j] = __builtin_amdgcn_mfma_f32_16x16x32_bf16(                  \
            af[i], bfr[j], acc[i][j], 0, 0, 0);                               \
  }

  for (int t4 = 0; t4 < 44; t4 += 4) {         // steps 0..43, prefetch 3..46
    GSTEP(0, 3, (t4 + 3) * BK, 1, WAIT_VM4);
    GSTEP(1, 0, (t4 + 4) * BK, 1, WAIT_VM4);
    GSTEP(2, 1, (t4 + 5) * BK, 1, WAIT_VM4);
    GSTEP(3, 2, (t4 + 6) * BK, 1, WAIT_VM4);
  }
  GSTEP(0, 3, 47 * BK, 1, WAIT_VM4);           // step 44, prefetch tile 47
  GSTEP(1, 0, 0, 0, WAIT_VM4);                 // step 45 (t46,t47 in flight)
  GSTEP(2, 0, 0, 0, WAIT_VM2);                 // step 46 (t47 in flight)
  GSTEP(3, 0, 0, 0, WAIT_VM0);                 // step 47: drain
#undef GSTEP

  // epilogue: write fp32 partial tile to P[kp] (no stats possible on partials)
  float* Pw = kp ? P1 : P0;
  #pragma unroll
  for (int j = 0; j < 2; ++j) {
    int gc = col0 + wc * 32 + j * 16 + frag_m;
    #pragma unroll
    for (int i = 0; i < 4; ++i) {
      int gr = row0 + wr * 64 + i * 16 + sel * 4;  // C/D: col=lane&15, row=(lane>>4)*4+r
      #pragma unroll
      for (int r = 0; r < 4; ++r)
        Pw[(size_t)(gr + r) * OUTF + gc] = acc[i][j][r];
    }
  }
}

// ---- 3. combine partials -> column stats (no Y write) ----------------------
// grid (32 colblk, 16 rowslab) x 256 thr. Reads P0+P1, emits per-slab col
// sum / sumsq.
__global__ void combine_stats(const float4* __restrict__ P0,
                              const float4* __restrict__ P1,
                              float* __restrict__ psum, float* __restrict__ psq) {
  __shared__ float red[2][8][4][32];        // [sum|sq][f4c][k][rr]
  const int t = threadIdx.x;
  const int f4c = t & 7, rr = t >> 3;
  const int cx = blockIdx.x, ry = blockIdx.y;
  float s[4] = {0,0,0,0}, s2[4] = {0,0,0,0};
  #pragma unroll
  for (int it = 0; it < 8; ++it) {
    int row = ry * 256 + it * 32 + rr;
    size_t idx = (size_t)row * 256 + cx * 8 + f4c;
    float4 a = P0[idx], b = P1[idx];
    float y0 = a.x + b.x, y1 = a.y + b.y, y2 = a.z + b.z, y3 = a.w + b.w;
    s[0] += y0; s[1] += y1; s[2] += y2; s[3] += y3;
    s2[0] += y0*y0; s2[1] += y1*y1; s2[2] += y2*y2; s2[3] += y3*y3;
  }
  #pragma unroll
  for (int k = 0; k < 4; ++k) { red[0][f4c][k][rr] = s[k]; red[1][f4c][k][rr] = s2[k]; }
  __syncthreads();
  if (t < 32) {
    float S = 0.f, SQ = 0.f;
    #pragma unroll 8
    for (int r = 0; r < 32; ++r) { S += red[0][t >> 2][t & 3][r]; SQ += red[1][t >> 2][t & 3][r]; }
    psum[ry * OUTF + cx * 32 + t] = S;
    psq [ry * OUTF + cx * 32 + t] = SQ;
  }
}

// ---- 4. final: combine + normalize + write Y -------------------------------
__global__ void bn_apply(const float4* __restrict__ P0, const float4* __restrict__ P1,
                         const float* __restrict__ psum, const float* __restrict__ psq,
                         const float* __restrict__ gamma, const float* __restrict__ beta,
                         float* __restrict__ Y) {
  __shared__ float sc[32], sh[32];
  const int cx = blockIdx.x, ry = blockIdx.y;
  const int t = threadIdx.x;
  if (t < 32) {
    float s = 0.f, s2 = 0.f;
    #pragma unroll
    for (int p = 0; p < 16; ++p) {
      s  += psum[p * OUTF + cx * 32 + t];
      s2 += psq [p * OUTF + cx * 32 + t];
    }
    float mean = s * (1.0f / B_ROWS);
    float var  = s2 * (1.0f / B_ROWS) - mean * mean;
    float scale = gamma[cx * 32 + t] * rsqrtf(var + BN_EPS);
    sc[t] = scale;
    sh[t] = beta[cx * 32 + t] - mean * scale;
  }
  __syncthreads();
  const int f4c = t & 7, rr = t >> 3;
  const int cb = f4c * 4;
  float s0 = sc[cb], s1 = sc[cb+1], s2 = sc[cb+2], s3 = sc[cb+3];
  float h0 = sh[cb], h1 = sh[cb+1], h2 = sh[cb+2], h3 = sh[cb+3];
  float4* Y4 = (float4*)Y;
  #pragma unroll
  for (int it = 0; it < 8; ++it) {
    int row = ry * 256 + it * 32 + rr;
    size_t idx = (size_t)row * 256 + cx * 8 + f4c;
    float4 a = P0[idx], b = P1[idx];
    float4 v;
    v.x = (a.x + b.x) * s0 + h0;
    v.y = (a.y + b.y) * s1 + h1;
    v.z = (a.z + b.z) * s2 + h2;
    v.w = (a.w + b.w) * s3 + h3;
    Y4[idx] = v;
  }
}

extern "C" void kernel_launch(void* const* d_in, const int* in_sizes, int n_in,
                              void* d_out, int out_size, void* d_ws, size_t ws_size,
                              hipStream_t stream) {
  const float* x     = (const float*)d_in[0];
  const float* c1    = (const float*)d_in[1];
  const float* c2    = (const float*)d_in[2];
  const float* c3    = (const float*)d_in[3];
  // d_in[4] = bias: unused — per-column constant cancels exactly in BatchNorm
  const float* gamma = (const float*)d_in[5];
  const float* beta  = (const float*)d_in[6];
  float* out = (float*)d_out;
  char* ws = (char*)d_ws;

  short* Xb   = (short*)(ws);                          // 25,165,824 B
  short* Wb   = (short*)(ws + 25165824);               //  6,291,456 B
  float* P0   = (float*)(ws + 31457280);               // 16,777,216 B
  float* P1   = (float*)(ws + 48234496);               // 16,777,216 B
  float* psum = (float*)(ws + 65011712);               //     64 KB
  float* psq  = (float*)(ws + 65077248);               //     64 KB

  prep_all<<<5120, 256, 0, stream>>>((const float4*)x, (const float4*)c1,
                                     (const float4*)c2, (const float4*)c3,
                                     Xb, Wb);

  gemm_poly<<<512, 512, 0, stream>>>(Xb, Wb, P0, P1);

  dim3 sgrid(32, 16);
  combine_stats<<<sgrid, 256, 0, stream>>>((const float4*)P0, (const float4*)P1,
                                           psum, psq);
  bn_apply<<<sgrid, 256, 0, stream>>>((const float4*)P0, (const float4*)P1,
                                      psum, psq, gamma, beta, out);
}